// Round 4
// baseline (245.499 us; speedup 1.0000x reference)
//
#include <hip/hip_runtime.h>

#define D_MAX 2048
#define EPSF 1e-6f
#define E5F 148.4131591f   // e^5

#define VBLK 256
#define VGRID 2048         // 8 blocks/CU x 4 waves = 32 waves/CU for the BW phase
#define DBLK 512
#define DGRID 1024         // 4 blocks/CU x 8 waves = 32 waves/CU

// LDS per-date u64 layout (low->high):  stp:24 @2^4 | pden:24 @2^10 | n0:8 | n1:8
// Global per-date u64 layout (low->high): n0:12 | n1:12 | pden:18 @2^4 | stp:22 @2^1
// R9: DECOMPOSITION. fusedk has been pinned at 78-80us across 4 structural variants
// (specialized/unified/non-atomic-flush/forced-MLP) and across L3-resident runs.
// No single pipe is saturated (VALU 20%, HBM 19%, LDS-conflict cycles ~4K/CU).
// Leading theory: ds_add_u64 backpressure fills the per-wave lgkm queue, stalling
// issue and starving the load stream (stall structure, not throughput). This round
// splits the dispatch so rocprof measures each subsystem alone:
//   volk = pure streaming reduce (64MB, no LDS)  -> expect 11-14us at 65-85% HBM
//   dirk = pure LDS histogram    (128MB, math byte-identical to R8's dir path)
// DS-wall hypothesis: dirk ~55-70us. Coupling hypothesis: dirk ~35-45us (net win).
// Either outcome pins Round 10's target.

__global__ void initk(unsigned long long* g_pd, double* sum_q, unsigned* n_valid,
                      const int* ndp) {
    int i = blockIdx.x * blockDim.x + threadIdx.x;
    int nd = ndp[0]; if (nd > D_MAX) nd = D_MAX;
    if (i == 0) { *sum_q = 0.0; *n_valid = 0u; }
    if (i < nd) g_pd[i] = 0ULL;
}

__device__ __forceinline__ void volElem(float p, float tg, double& accq, unsigned& accn) {
    if (tg > EPSF && p > EPSF) {   // NaN tgt fails compare, matching ~isnan & >eps
        float pv = fmaxf(p * p, EPSF);
        float tv = fmaxf(tg * tg, EPSF);
        accq += (double)(__fdividef(tv, pv) + __logf(pv));
        accn++;
    }
}

__device__ __forceinline__ void volGroup(const float4& p4, const float4& t4,
                                         double& accq, unsigned& accn) {
    volElem(p4.x, t4.x, accq, accn);
    volElem(p4.y, t4.y, accq, accn);
    volElem(p4.z, t4.z, accq, accn);
    volElem(p4.w, t4.w, accq, accn);
}

__device__ __forceinline__ void dirElem(int lb, int d, float l0, float l1,
                                        unsigned long long* s_pack) {
    if (lb >= 0) {
        // p1 = softmax(logits)[:,1]; segment-max shift cancels exactly in the ratios
        float p1 = __fdividef(1.0f, 1.0f + __expf(l0 - l1));
        float pe = __expf(p1);                 // in (1, e): no overflow
        float w  = (lb >= 1) ? E5F * p1 : p1;  // te * p1, te in {1, e^5}
        unsigned stp_i = (unsigned)(w * 16.0f + 0.5f);
        unsigned pd_i  = (unsigned)(pe * 1024.0f + 0.5f);
        unsigned long long inc = (unsigned long long)stp_i
                               | ((unsigned long long)pd_i << 24)
                               | (1ULL << (48 + 8 * (lb >= 1)));
        atomicAdd(&s_pack[d], inc);
    }
}

__device__ __forceinline__ void dirGroup(const int4& l4, const int4& d4,
                                         const float4& ga, const float4& gb,
                                         unsigned long long* s_pack) {
    dirElem(l4.x, d4.x, ga.x, ga.y, s_pack);
    dirElem(l4.y, d4.y, ga.z, ga.w, s_pack);
    dirElem(l4.z, d4.z, gb.x, gb.y, s_pack);
    dirElem(l4.w, d4.w, gb.z, gb.w, s_pack);
}

// ---------------- volk: pure streaming QLIKE reduce, no LDS histogram ----------------
__global__ __launch_bounds__(VBLK, 8)
void volk(const float4* __restrict__ vp4, const float4* __restrict__ vt4, int B,
          double* __restrict__ sum_q, unsigned* __restrict__ n_valid) {
    __shared__ double s_q[VBLK / 64];
    __shared__ unsigned s_n[VBLK / 64];
    int B4 = B >> 2;
    const int stride = VGRID * VBLK;
    int tid = blockIdx.x * VBLK + threadIdx.x;
    double accq = 0.0;
    unsigned accn = 0u;

    int n = B4 / stride;
    int k = 0;
    for (; k + 2 <= n; k += 2) {
        int i0 = tid + k * stride, i1 = i0 + stride;
        float4 p0 = vp4[i0], t0 = vt4[i0];
        float4 p1 = vp4[i1], t1 = vt4[i1];
        __builtin_amdgcn_sched_barrier(0);
        volGroup(p0, t0, accq, accn);
        volGroup(p1, t1, accq, accn);
    }
    for (; k < n; k++) {
        int i = tid + k * stride;
        volGroup(vp4[i], vt4[i], accq, accn);
    }
    for (int i = tid + n * stride; i < B4; i += stride)
        volGroup(vp4[i], vt4[i], accq, accn);
    int rem = B & 3;
    if (tid < rem) {
        int j = (B4 << 2) + tid;
        volElem(((const float*)vp4)[j], ((const float*)vt4)[j], accq, accn);
    }

    for (int o = 32; o > 0; o >>= 1) {
        accq += __shfl_down(accq, o);
        accn += __shfl_down(accn, o);
    }
    int lane = threadIdx.x & 63, wv = threadIdx.x >> 6;
    if (lane == 0) { s_q[wv] = accq; s_n[wv] = accn; }
    __syncthreads();
    if (threadIdx.x == 0) {
        double q = 0.0; unsigned nn = 0u;
        for (int w = 0; w < VBLK / 64; w++) { q += s_q[w]; nn += s_n[w]; }
        atomicAdd(sum_q, q);
        atomicAdd(n_valid, nn);
    }
}

// ---------------- dirk: pure per-date LDS histogram (math identical to R8) ----------------
__global__ __launch_bounds__(DBLK, 8)
void dirk(const float4* __restrict__ lg4, const int4* __restrict__ lab4,
          const int4* __restrict__ dt4, int B,
          unsigned long long* __restrict__ g_pd, const int* __restrict__ ndp) {
    __shared__ unsigned long long s_pack[D_MAX];
    int nd = ndp[0]; if (nd > D_MAX) nd = D_MAX;
    int B4 = B >> 2;

    for (int d = threadIdx.x; d < nd; d += DBLK) s_pack[d] = 0ULL;
    __syncthreads();

    const int stride = DGRID * DBLK;
    int tid = blockIdx.x * DBLK + threadIdx.x;

    int n = B4 / stride;
    int k = 0;
    for (; k + 2 <= n; k += 2) {
        int i0 = tid + k * stride, i1 = i0 + stride;
        int4   la0 = lab4[i0], da0 = dt4[i0];
        float4 ga0 = lg4[2 * i0], gb0 = lg4[2 * i0 + 1];
        int4   la1 = lab4[i1], da1 = dt4[i1];
        float4 ga1 = lg4[2 * i1], gb1 = lg4[2 * i1 + 1];
        __builtin_amdgcn_sched_barrier(0);
        dirGroup(la0, da0, ga0, gb0, s_pack);
        dirGroup(la1, da1, ga1, gb1, s_pack);
    }
    for (; k < n; k++) {
        int i = tid + k * stride;
        dirGroup(lab4[i], dt4[i], lg4[2 * i], lg4[2 * i + 1], s_pack);
    }
    for (int i = tid + n * stride; i < B4; i += stride)
        dirGroup(lab4[i], dt4[i], lg4[2 * i], lg4[2 * i + 1], s_pack);
    int rem = B & 3;
    if (tid < rem) {
        int j = (B4 << 2) + tid;
        dirElem(((const int*)lab4)[j], ((const int*)dt4)[j],
                ((const float*)lg4)[2 * j], ((const float*)lg4)[2 * j + 1], s_pack);
    }
    __syncthreads();

    // flush: ONE packed u64 global atomic per nonzero date, phase-staggered
    int start = (blockIdx.x & 7) * DBLK;
    if (start >= nd) start %= nd;
    for (int kk = 0; kk < (nd + DBLK - 1) / DBLK; kk++) {
        int d0 = threadIdx.x + kk * DBLK;
        if (d0 < nd) {
            int d = d0 + start;
            if (d >= nd) d -= nd;
            unsigned long long c = s_pack[d];
            if (c) {
                unsigned stp24 = (unsigned)(c & 0xFFFFFFu);          // @2^4
                unsigned pd24  = (unsigned)((c >> 24) & 0xFFFFFFu);  // @2^10
                unsigned n0 = (unsigned)((c >> 48) & 0xFFu);
                unsigned n1 = (unsigned)(c >> 56);
                unsigned pd4  = (pd24 + 32u) >> 6;   // -> @2^4
                unsigned stp1 = (stp24 + 4u) >> 3;   // -> @2^1
                unsigned long long ginc = (unsigned long long)n0
                                        | ((unsigned long long)n1 << 12)
                                        | ((unsigned long long)pd4 << 24)
                                        | ((unsigned long long)stp1 << 42);
                atomicAdd(&g_pd[d], ginc);
            }
        }
    }
}

__global__ void finalk(const unsigned long long* __restrict__ g_pd, const int* __restrict__ ndp,
                       const double* __restrict__ sum_q, const unsigned* __restrict__ n_valid,
                       float* __restrict__ out) {
    __shared__ double s_ce[4];
    __shared__ unsigned s_c[4];
    int nd = ndp[0]; if (nd > D_MAX) nd = D_MAX;
    double ce = 0.0; unsigned cnt = 0u;
    for (int d = threadIdx.x; d < nd; d += 256) {
        unsigned long long pk = g_pd[d];
        unsigned n0 = (unsigned)(pk & 0xFFFu);
        unsigned n1 = (unsigned)((pk >> 12) & 0xFFFu);
        if (n0 + n1 >= 2u) {
            float pden = (float)((pk >> 24) & 0x3FFFFu) * (1.0f / 16.0f);
            float stp  = (float)(pk >> 42) * 0.5f;
            float td   = (float)n0 + (float)n1 * E5F;
            ce += (double)(__logf(fmaxf(pden, 1e-30f)) - stp / td);
            cnt++;
        }
    }
    for (int o = 32; o > 0; o >>= 1) { ce += __shfl_down(ce, o); cnt += __shfl_down(cnt, o); }
    int lane = threadIdx.x & 63, w = threadIdx.x >> 6;
    if (lane == 0) { s_ce[w] = ce; s_c[w] = cnt; }
    __syncthreads();
    if (threadIdx.x == 0) {
        double dce = s_ce[0] + s_ce[1] + s_ce[2] + s_ce[3];
        unsigned n = s_c[0] + s_c[1] + s_c[2] + s_c[3];
        unsigned nv = *n_valid;
        double vol = nv ? (*sum_q) / (double)nv : 0.0;
        double dir = dce / (double)(n ? n : 1u);
        out[0] = (float)(0.85 * vol + 0.15 * dir);
        out[1] = (float)vol;
        out[2] = (float)dir;
    }
}

extern "C" void kernel_launch(void* const* d_in, const int* in_sizes, int n_in,
                              void* d_out, int out_size, void* d_ws, size_t ws_size,
                              hipStream_t stream) {
    const float4* lg4 = (const float4*)d_in[0];
    const int4* lab4  = (const int4*)d_in[1];
    const float4* vp4 = (const float4*)d_in[2];
    const float4* vt4 = (const float4*)d_in[3];
    const int4* dt4   = (const int4*)d_in[4];
    const int* ndp    = (const int*)d_in[5];
    int B = in_sizes[1];
    float* out = (float*)d_out;

    char* ws = (char*)d_ws;
    double*   sum_q   = (double*)(ws + 0);
    unsigned* n_valid = (unsigned*)(ws + 8);
    unsigned long long* g_pd = (unsigned long long*)(ws + 64);  // 16 KB

    initk<<<(D_MAX + 255) / 256, 256, 0, stream>>>(g_pd, sum_q, n_valid, ndp);
    volk<<<VGRID, VBLK, 0, stream>>>(vp4, vt4, B, sum_q, n_valid);
    dirk<<<DGRID, DBLK, 0, stream>>>(lg4, lab4, dt4, B, g_pd, ndp);
    finalk<<<1, 256, 0, stream>>>(g_pd, ndp, sum_q, n_valid, out);
}